// Round 3
// baseline (1245.677 us; speedup 1.0000x reference)
//
#include <hip/hip_runtime.h>
#include <hip/hip_bf16.h>

typedef __hip_bfloat16 bf16;

#define Bb   128
#define MEMm 40

__device__ __forceinline__ float LD(const void* p, size_t i, int f32) {
    return f32 ? ((const float*)p)[i] : __bfloat162float(((const bf16*)p)[i]);
}
__device__ __forceinline__ int LDB(const void* p, int i, int isbyte) {
    return isbyte ? (int)((const unsigned char*)p)[i] : ((const int*)p)[i];
}

// flags[0]=float32 inputs, flags[1]=src_mask byte-packed, flags[2]=notdone byte-packed
__global__ void detect_kernel(const void* __restrict__ x,
                              const void* __restrict__ src_mask,
                              const void* __restrict__ notdone,
                              int* __restrict__ flags) {
    __shared__ int s[3];
    const int t = threadIdx.x;
    if (t < 3) s[t] = 0;
    __syncthreads();
    const bf16* xb = (const bf16*)x;
    int bad = 0;
    for (int i = t; i < 4096; i += 256) {
        // EVEN positions: for f32 data these are low-mantissa halves -> random
        // bf16 bit patterns (huge/NaN with high probability). For genuine bf16
        // data they are real N(0,1) samples, always tiny.
        float v = __bfloat162float(xb[2 * i]);
        if (!(fabsf(v) < 1e4f)) bad = 1;   // catches NaN too
    }
    if (bad) atomicOr(&s[0], 1);
    int mb = 0;
    const unsigned* mi = (const unsigned*)src_mask;
    for (int i = t; i < 1280; i += 256) if (mi[i] > 1u) mb = 1;
    if (mb) atomicOr(&s[1], 1);
    int nb = 0;
    const unsigned* ni = (const unsigned*)notdone;
    for (int i = t; i < 32; i += 256) if (ni[i] > 1u) nb = 1;
    if (nb) atomicOr(&s[2], 1);
    __syncthreads();
    if (t < 3) flags[t] = s[t];
}

__global__ void bias_kernel(const void* __restrict__ src_mask,
                            const void* __restrict__ notdone,
                            const int* __restrict__ flags,
                            float* __restrict__ biasb) {
    int idx = blockIdx.x * 256 + threadIdx.x;
    if (idx >= Bb * MEMm) return;
    const int mbyte = flags[1], ndbyte = flags[2];
    int b = idx / MEMm, m = idx - b * MEMm;
    float v;
    if (m == MEMm - 1) v = 3.0f;
    else {
        bool masked = (LDB(src_mask, b * MEMm + m + 1, mbyte) != 0) ||
                      (LDB(notdone, b, ndbyte) == 0);
        v = masked ? -1e9f : 0.f;
    }
    biasb[idx] = v;
}

__global__ void init_prevout_kernel(const void* __restrict__ h0,
                                    const void* __restrict__ notdone,
                                    const int* __restrict__ flags,
                                    float* __restrict__ outb, size_t off) {
    int idx = blockIdx.x * 256 + threadIdx.x;
    if (idx >= Bb * 4096) return;
    const int isf32 = flags[0], ndbyte = flags[2];
    int b = idx >> 12;
    float nd = (LDB(notdone, b, ndbyte) != 0) ? 1.f : 0.f;
    outb[idx] = LD(h0, off + idx, isf32) * nd;
}

__global__ void build_cin_kernel(const void* __restrict__ x,
                                 const float* __restrict__ prev_out,
                                 const void* __restrict__ h0,
                                 const void* __restrict__ notdone,
                                 const int* __restrict__ flags,
                                 float* __restrict__ cin, size_t hoff) {
    int idx = blockIdx.x * 256 + threadIdx.x;
    if (idx >= Bb * 192 * 64) return;
    const int isf32 = flags[0], ndbyte = flags[2];
    int b = idx / (192 * 64);
    int r = idx - b * (192 * 64);
    int c = r >> 6, s = r & 63;
    float v;
    if (c < 64)       v = LD(x, (size_t)b * 4096 + c * 64 + s, isf32);
    else if (c < 128) v = prev_out[(size_t)b * 4096 + (c - 64) * 64 + s];
    else {
        float nd = (LDB(notdone, b, ndbyte) != 0) ? 1.f : 0.f;
        v = LD(h0, hoff + (size_t)b * 4096 + (c - 128) * 64 + s, isf32) * nd;
    }
    cin[idx] = v;
}

__global__ __launch_bounds__(256) void conv3x3_kernel(
    const float* __restrict__ in, int inCs,
    const void* __restrict__ w,
    const void* __restrict__ bias,
    const int* __restrict__ flags,
    float* __restrict__ out, int Cin, int Cout,
    size_t woff, size_t boff) {
    extern __shared__ float lds[];
    float* inlds = lds;          // 4096
    float* wlds  = lds + 4096;   // 9216
    const int t = threadIdx.x;
    const int isf32 = flags[0];
    const int s = t & 63, g = t >> 6;
    const int b = blockIdx.y;
    const int co_base = blockIdx.x * 16;
    const int y = s >> 3, x0 = s & 7;
    float acc0 = LD(bias, boff + co_base + g * 4 + 0, isf32);
    float acc1 = LD(bias, boff + co_base + g * 4 + 1, isf32);
    float acc2 = LD(bias, boff + co_base + g * 4 + 2, isf32);
    float acc3 = LD(bias, boff + co_base + g * 4 + 3, isf32);
    for (int ci0 = 0; ci0 < Cin; ci0 += 64) {
        __syncthreads();
        for (int i = t; i < 4096; i += 256)
            inlds[i] = in[((size_t)b * inCs + ci0) * 64 + i];
        if (isf32) {
            for (int i = t; i < 9216; i += 256) {
                int co_idx = i & 15; int r = i >> 4; int cil = r / 9; int tap = r - cil * 9;
                wlds[i] = ((const float*)w)[woff + ((size_t)(co_base + co_idx) * Cin + ci0 + cil) * 9 + tap];
            }
        } else {
            for (int i = t; i < 9216; i += 256) {
                int co_idx = i & 15; int r = i >> 4; int cil = r / 9; int tap = r - cil * 9;
                wlds[i] = __bfloat162float(((const bf16*)w)[woff + ((size_t)(co_base + co_idx) * Cin + ci0 + cil) * 9 + tap]);
            }
        }
        __syncthreads();
        for (int cil = 0; cil < 64; ++cil) {
            const float* ip = inlds + cil * 64;
            float nb[9];
#pragma unroll
            for (int tap = 0; tap < 9; ++tap) {
                int dy = tap / 3 - 1, dx = tap % 3 - 1;
                int yy = y + dy, xx = x0 + dx;
                nb[tap] = ((unsigned)yy < 8u && (unsigned)xx < 8u) ? ip[yy * 8 + xx] : 0.f;
            }
            const float* wp = wlds + cil * 144 + g * 4;
#pragma unroll
            for (int tap = 0; tap < 9; ++tap) {
                float4 wv = *(const float4*)(wp + tap * 16);
                acc0 += nb[tap] * wv.x;
                acc1 += nb[tap] * wv.y;
                acc2 += nb[tap] * wv.z;
                acc3 += nb[tap] * wv.w;
            }
        }
    }
    size_t ob = ((size_t)b * Cout + co_base + g * 4) * 64 + s;
    out[ob]          = acc0;
    out[ob + 64]     = acc1;
    out[ob + 128]    = acc2;
    out[ob + 192]    = acc3;
}

__global__ __launch_bounds__(256) void attn_kernel(
    const float* __restrict__ kqv,
    const void* __restrict__ k0,
    const void* __restrict__ v0,
    const void* __restrict__ pw,    // (L, MEM, NH*THD)
    const void* __restrict__ pb,    // (L, MEM, NH)
    const float* __restrict__ biasb,
    const int* __restrict__ flags,
    float* __restrict__ attn_out,
    size_t kvoff, size_t pwoff, size_t pboff) {
    __shared__ float q[512], kl[512], vl[512], sc[40], wexp[40];
    const int t = threadIdx.x;
    const int isf32 = flags[0];
    const int b = blockIdx.x >> 3, h = blockIdx.x & 7;
    const size_t kqb = (size_t)b * 192 * 64;
    for (int d = t; d < 512; d += 256) {
        int hd = d >> 6, ss = d & 63;
        q[d]  = kqv[kqb + (h * 24 + 8 + hd) * 64 + ss] * 0.044194173824159216f;
        kl[d] = kqv[kqb + (h * 24 + 0 + hd) * 64 + ss];
        vl[d] = kqv[kqb + (h * 24 + 16 + hd) * 64 + ss];
    }
    __syncthreads();
    const int wid = t >> 6, lane = t & 63;
    const size_t kvbase = kvoff + ((size_t)(b * 8 + h)) * (size_t)(40 * 512);
    for (int m = wid; m < 40; m += 4) {
        float p = 0.f;
        if (isf32) {
#pragma unroll
            for (int i = 0; i < 8; ++i) {
                int d = lane + 64 * i;
                float kc = (m < 39) ? ((const float*)k0)[kvbase + (size_t)(m + 1) * 512 + d] : kl[d];
                kc += ((const float*)pw)[pwoff + (size_t)m * 4096 + h * 512 + d];
                p += q[d] * kc;
            }
        } else {
#pragma unroll
            for (int i = 0; i < 8; ++i) {
                int d = lane + 64 * i;
                float kc = (m < 39) ? __bfloat162float(((const bf16*)k0)[kvbase + (size_t)(m + 1) * 512 + d]) : kl[d];
                kc += __bfloat162float(((const bf16*)pw)[pwoff + (size_t)m * 4096 + h * 512 + d]);
                p += q[d] * kc;
            }
        }
#pragma unroll
        for (int off = 32; off > 0; off >>= 1) p += __shfl_down(p, off, 64);
        if (lane == 0)
            sc[m] = p + biasb[b * 40 + m] + LD(pb, pboff + m * 8 + h, isf32);
    }
    __syncthreads();
    float mx = -1e30f;
    for (int m = 0; m < 40; ++m) mx = fmaxf(mx, sc[m]);
    if (t < 40) wexp[t] = __expf(sc[t] - mx);
    __syncthreads();
    float sum = 0.f;
    for (int m = 0; m < 40; ++m) sum += wexp[m];
    float rs = 1.f / sum;
    for (int d = t; d < 512; d += 256) {
        float acc = 0.f;
        if (isf32) {
            for (int m = 0; m < 39; ++m)
                acc += wexp[m] * ((const float*)v0)[kvbase + (size_t)(m + 1) * 512 + d];
        } else {
            for (int m = 0; m < 39; ++m)
                acc += wexp[m] * __bfloat162float(((const bf16*)v0)[kvbase + (size_t)(m + 1) * 512 + d]);
        }
        acc += wexp[39] * vl[d];
        acc *= rs;
        attn_out[(size_t)b * 4096 + (h * 8 + (d >> 6)) * 64 + (d & 63)] = acc;
    }
}

__global__ __launch_bounds__(256) void ln_final_kernel(
    const float* __restrict__ convo,
    const void* __restrict__ x,
    const float* __restrict__ gates,
    const void* __restrict__ c0,
    const void* __restrict__ notdone,
    const void* __restrict__ lnw,
    const void* __restrict__ lnb,
    const int* __restrict__ flags,
    float* __restrict__ out_buf,
    void* __restrict__ dout, int write_out,
    size_t coff, size_t lnoff) {
    __shared__ float red[8];
    __shared__ float stats[2];
    const int t = threadIdx.x, b = blockIdx.x;
    const int isf32 = flags[0], ndbyte = flags[2];
    const size_t base = (size_t)b * 4096;
    float v[16];
    float sum = 0.f, sumsq = 0.f;
#pragma unroll
    for (int k = 0; k < 16; ++k) {
        int i = t + 256 * k;
        float val = convo[base + i] + LD(x, base + i, isf32);
        v[k] = val; sum += val; sumsq += val * val;
    }
#pragma unroll
    for (int off = 32; off > 0; off >>= 1) {
        sum   += __shfl_down(sum, off, 64);
        sumsq += __shfl_down(sumsq, off, 64);
    }
    const int wid = t >> 6, lane = t & 63;
    if (lane == 0) { red[wid] = sum; red[4 + wid] = sumsq; }
    __syncthreads();
    if (t == 0) {
        float ts = red[0] + red[1] + red[2] + red[3];
        float tq = red[4] + red[5] + red[6] + red[7];
        float mu = ts * (1.f / 4096.f);
        float var = tq * (1.f / 4096.f) - mu * mu;
        stats[0] = mu; stats[1] = rsqrtf(fmaxf(var, 0.f) + 1e-5f);
    }
    __syncthreads();
    float mu = stats[0], rstd = stats[1];
    float nd = (LDB(notdone, b, ndbyte) != 0) ? 1.f : 0.f;
    const size_t gbase = (size_t)b * 320 * 64;
#pragma unroll
    for (int k = 0; k < 16; ++k) {
        int i = t + 256 * k;
        int c = i >> 6, s = i & 63;
        float aon = (v[k] - mu) * rstd * LD(lnw, lnoff + i, isf32) + LD(lnb, lnoff + i, isf32);
        float gi = gates[gbase + (size_t)(c      ) * 64 + s];
        float gf = gates[gbase + (size_t)(c +  64) * 64 + s];
        float go = gates[gbase + (size_t)(c + 128) * 64 + s];
        float gg = gates[gbase + (size_t)(c + 192) * 64 + s];
        float ga = gates[gbase + (size_t)(c + 256) * 64 + s];
        gi = 1.f / (1.f + __expf(-gi));
        gf = 1.f / (1.f + __expf(-gf));
        go = 1.f / (1.f + __expf(-go));
        gg = tanhf(gg);
        ga = 1.f / (1.f + __expf(-ga));
        float cc = LD(c0, coff + base + i, isf32) * nd;
        float cn = gf * cc + gi * gg + ga * tanhf(aon);
        float o  = go * tanhf(cn);
        out_buf[base + i] = o;
        if (write_out) {
            if (isf32) ((float*)dout)[base + i] = o;
            else       ((bf16*)dout)[base + i] = __float2bfloat16(o);
        }
    }
}

extern "C" void kernel_launch(void* const* d_in, const int* in_sizes, int n_in,
                              void* d_out, int out_size, void* d_ws, size_t ws_size,
                              hipStream_t stream) {
    const void* x      = d_in[0];
    const void* h0     = d_in[1];
    const void* c0     = d_in[2];
    const void* k0     = d_in[3];
    const void* v0     = d_in[4];
    const void* src_mask = d_in[5];
    const void* notdone  = d_in[6];
    const void* main_w = d_in[7];
    const void* main_b = d_in[8];
    const void* proj_w = d_in[9];
    const void* proj_b = d_in[10];
    const void* out_w  = d_in[11];
    const void* out_b  = d_in[12];
    const void* ln_w   = d_in[13];
    const void* ln_b   = d_in[14];
    const void* pos_w  = d_in[15];
    const void* pos_b  = d_in[16];

    float* wsf       = (float*)d_ws;
    int*   flags     = (int*)d_ws;                // ints [0..3]
    float* bias_buf  = wsf + 8;                   // 5120
    float* out_buf   = wsf + 8192;                // 524288
    float* cin_buf   = out_buf + 524288;          // 1572864
    float* gates_buf = cin_buf + 1572864;         // 2621440
    float* kqv_buf   = gates_buf + 2621440;       // 1572864
    float* attn_buf  = cin_buf;                   // alias: cin dead after proj conv
    float* convo_buf = cin_buf + 524288;          // alias

    detect_kernel<<<1, 256, 0, stream>>>(x, src_mask, notdone, flags);
    bias_kernel<<<20, 256, 0, stream>>>(src_mask, notdone, flags, bias_buf);
    init_prevout_kernel<<<2048, 256, 0, stream>>>(h0, notdone, flags, out_buf,
                                                  (size_t)524288);
    for (int n = 0; n < 2; ++n) {
        build_cin_kernel<<<6144, 256, 0, stream>>>(x, out_buf, h0, notdone, flags,
                                                   cin_buf, (size_t)n * 524288);
        conv3x3_kernel<<<dim3(20, 128), 256, 53248, stream>>>(
            cin_buf, 192, main_w, main_b, flags, gates_buf, 192, 320,
            (size_t)n * 552960, (size_t)n * 320);
        conv3x3_kernel<<<dim3(12, 128), 256, 53248, stream>>>(
            cin_buf, 192, proj_w, proj_b, flags, kqv_buf, 128, 192,
            (size_t)n * 221184, (size_t)n * 192);
        attn_kernel<<<1024, 256, 0, stream>>>(
            kqv_buf, k0, v0, pos_w, pos_b, bias_buf, flags, attn_buf,
            (size_t)n * 20971520, (size_t)n * 163840, (size_t)n * 320);
        conv3x3_kernel<<<dim3(4, 128), 256, 53248, stream>>>(
            attn_buf, 64, out_w, out_b, flags, convo_buf, 64, 64,
            (size_t)n * 36864, (size_t)n * 64);
        ln_final_kernel<<<128, 256, 0, stream>>>(
            convo_buf, x, gates_buf, c0, notdone, ln_w, ln_b, flags,
            out_buf, d_out, (n == 1) ? 1 : 0,
            (size_t)n * 524288, (size_t)n * 4096);
    }
}

// Round 4
// 638.585 us; speedup vs baseline: 1.9507x; 1.9507x over previous
//
#include <hip/hip_runtime.h>
#include <hip/hip_bf16.h>

typedef __hip_bfloat16 bf16;
typedef unsigned short u16;
typedef __attribute__((ext_vector_type(8))) short short8;
typedef __attribute__((ext_vector_type(4))) float f32x4;

#define Bb   128
#define MEMm 40

__device__ __forceinline__ float LD(const void* p, size_t i, int f32) {
    return f32 ? ((const float*)p)[i] : __bfloat162float(((const bf16*)p)[i]);
}
__device__ __forceinline__ int LDB(const void* p, int i, int isbyte) {
    return isbyte ? (int)((const unsigned char*)p)[i] : ((const int*)p)[i];
}
__device__ __forceinline__ void SPLIT(float v, u16& hi, u16& lo) {
    bf16 h = __float2bfloat16(v);
    float r = v - __bfloat162float(h);
    bf16 l = __float2bfloat16(r);
    hi = *(u16*)&h; lo = *(u16*)&l;
}

// flags[0]=float32 inputs, flags[1]=src_mask byte-packed, flags[2]=notdone byte-packed
__global__ void detect_kernel(const void* __restrict__ x,
                              const void* __restrict__ src_mask,
                              const void* __restrict__ notdone,
                              int* __restrict__ flags) {
    __shared__ int s[3];
    const int t = threadIdx.x;
    if (t < 3) s[t] = 0;
    __syncthreads();
    const bf16* xb = (const bf16*)x;
    int bad = 0;
    for (int i = t; i < 4096; i += 256) {
        float v = __bfloat162float(xb[2 * i]);   // even halves: garbage iff f32
        if (!(fabsf(v) < 1e4f)) bad = 1;
    }
    if (bad) atomicOr(&s[0], 1);
    int mb = 0;
    const unsigned* mi = (const unsigned*)src_mask;
    for (int i = t; i < 1280; i += 256) if (mi[i] > 1u) mb = 1;
    if (mb) atomicOr(&s[1], 1);
    int nb = 0;
    const unsigned* ni = (const unsigned*)notdone;
    for (int i = t; i < 32; i += 256) if (ni[i] > 1u) nb = 1;
    if (nb) atomicOr(&s[2], 1);
    __syncthreads();
    if (t < 3) flags[t] = s[t];
}

__global__ void bias_kernel(const void* __restrict__ src_mask,
                            const void* __restrict__ notdone,
                            const int* __restrict__ flags,
                            float* __restrict__ biasb) {
    int idx = blockIdx.x * 256 + threadIdx.x;
    if (idx >= Bb * MEMm) return;
    const int mbyte = flags[1], ndbyte = flags[2];
    int b = idx / MEMm, m = idx - b * MEMm;
    float v;
    if (m == MEMm - 1) v = 3.0f;
    else {
        bool masked = (LDB(src_mask, b * MEMm + m + 1, mbyte) != 0) ||
                      (LDB(notdone, b, ndbyte) == 0);
        v = masked ? -1e9f : 0.f;
    }
    biasb[idx] = v;
}

__global__ void init_prevout_kernel(const void* __restrict__ h0,
                                    const void* __restrict__ notdone,
                                    const int* __restrict__ flags,
                                    float* __restrict__ outb, size_t off) {
    int idx = blockIdx.x * 256 + threadIdx.x;
    if (idx >= Bb * 4096) return;
    const int isf32 = flags[0], ndbyte = flags[2];
    int b = idx >> 12;
    float nd = (LDB(notdone, b, ndbyte) != 0) ? 1.f : 0.f;
    outb[idx] = LD(h0, off + idx, isf32) * nd;
}

// repack conv weights [co][ci][3][3] -> [tap][co][ci], hi/lo bf16 split.
// regions in dst: main @0 (552960), proj @552960 (221184), out @774144 (36864)
__global__ void repack_w_kernel(const void* __restrict__ mw,
                                const void* __restrict__ pw,
                                const void* __restrict__ ow,
                                const int* __restrict__ flags,
                                u16* __restrict__ whi, u16* __restrict__ wlo,
                                int layer) {
    int i = blockIdx.x * 256 + threadIdx.x;
    if (i >= 811008) return;
    const int isf32 = flags[0];
    float v;
    if (i < 552960) {
        int tap = i / 61440, r = i - tap * 61440, co = r / 192, ci = r - co * 192;
        v = LD(mw, (size_t)layer * 552960 + ((size_t)co * 192 + ci) * 9 + tap, isf32);
    } else if (i < 774144) {
        int j = i - 552960;
        int tap = j / 24576, r = j - tap * 24576, co = r / 128, ci = r - co * 128;
        v = LD(pw, (size_t)layer * 221184 + ((size_t)co * 128 + ci) * 9 + tap, isf32);
    } else {
        int j = i - 774144;
        int tap = j / 4096, r = j - tap * 4096, co = r / 64, ci = r - co * 64;
        v = LD(ow, (size_t)layer * 36864 + ((size_t)co * 64 + ci) * 9 + tap, isf32);
    }
    u16 h, l; SPLIT(v, h, l);
    whi[i] = h; wlo[i] = l;
}

// build concat input [x, prev_out, h_cur*nd] transposed to [b][px][192], hi/lo bf16
__global__ __launch_bounds__(256) void build_cin_t_kernel(
    const void* __restrict__ x, const float* __restrict__ prev_out,
    const void* __restrict__ h0, const void* __restrict__ notdone,
    const int* __restrict__ flags,
    u16* __restrict__ cin_hi, u16* __restrict__ cin_lo, size_t hoff) {
    __shared__ float sb[192 * 65];
    const int t = threadIdx.x, b = blockIdx.x;
    const int isf32 = flags[0], ndbyte = flags[2];
    float nd = (LDB(notdone, b, ndbyte) != 0) ? 1.f : 0.f;
    for (int i = t; i < 12288; i += 256) {
        int c = i >> 6, px = i & 63;
        float v;
        if (c < 64)       v = LD(x, (size_t)b * 4096 + i, isf32);
        else if (c < 128) v = prev_out[(size_t)b * 4096 + i - 4096];
        else              v = LD(h0, hoff + (size_t)b * 4096 + i - 8192, isf32) * nd;
        sb[c * 65 + px] = v;
    }
    __syncthreads();
    size_t base = (size_t)b * 12288;
    for (int i = t; i < 12288; i += 256) {
        int px = i / 192, c = i - px * 192;
        float v = sb[c * 65 + px];
        u16 h, l; SPLIT(v, h, l);
        cin_hi[base + i] = h; cin_lo[base + i] = l;
    }
}

// ---------------------------------------------------------------- MFMA conv
// 9-tap implicit GEMM, f32 via bf16 hi/lo split (3 MFMAs per tile pair).
// block: 4 waves, wave w = batch mblk*4+w, tile 64px x 64co.
struct ConvArgs {
    const u16 *Ahi, *Alo;            // [B][64][Astr]
    const u16 *WhiA, *WloA, *WhiB, *WloB;  // [9][Cout][Kci]
    const void *biasA, *biasB;
    float *OutA, *OutB;              // [B][Cout][64]
    long long boffA, boffB;
    int Astr, KciA, KciB, CoutA, CoutB, ntA, NT;
};

__global__ __launch_bounds__(256) void conv_mfma_kernel(ConvArgs g,
                                                        const int* __restrict__ flags) {
    __shared__ __align__(16) u16 Alds[4][2][2600];   // [wave][hi/lo][row*40+ci], row 64 = zeros
    __shared__ __align__(16) u16 Wlds[2][2][2560];   // [par][hi/lo][co*40+ci]
    const int t = threadIdx.x, w = t >> 6, lane = t & 63;
    const int bx = blockIdx.x;
    const int nt = bx % g.NT, mblk = bx / g.NT;
    const bool isA = (nt < g.ntA);
    const u16* Whi = isA ? g.WhiA : g.WhiB;
    const u16* Wlo = isA ? g.WloA : g.WloB;
    const int Kci  = isA ? g.KciA : g.KciB;
    const int CoutT= isA ? g.CoutA : g.CoutB;
    float* Out     = isA ? g.OutA : g.OutB;
    const void* bias = isA ? g.biasA : g.biasB;
    const long long boff = isA ? g.boffA : g.boffB;
    const int n0 = (isA ? nt : nt - g.ntA) * 64;
    const int b = mblk * 4 + w;
    const int NITER = (Kci >> 5) * 9;
    const int isf32 = flags[0];

    if (lane < 40) { Alds[w][0][2560 + lane] = 0; Alds[w][1][2560 + lane] = 0; }

    f32x4 acc[4][4];
#pragma unroll
    for (int i = 0; i < 4; ++i)
#pragma unroll
        for (int j = 0; j < 4; ++j) { f32x4 z = {0.f, 0.f, 0.f, 0.f}; acc[i][j] = z; }

    const int co_l = t >> 2, jj = t & 3;
    uint4 hv, lv;
    auto issueW = [&](int it) {
        int kc = it / 9, tap = it - kc * 9;
        size_t o = ((size_t)(tap * CoutT + n0 + co_l)) * Kci + kc * 32 + jj * 8;
        hv = *(const uint4*)(Whi + o);
        lv = *(const uint4*)(Wlo + o);
    };

    issueW(0);
    for (int it = 0; it < NITER; ++it) {
        const int kc = it / 9, tap = it - kc * 9;
        const int par = it & 1;
        // commit prefetched W to LDS
        *(uint4*)&Wlds[par][0][co_l * 40 + jj * 8] = hv;
        *(uint4*)&Wlds[par][1][co_l * 40 + jj * 8] = lv;
        __syncthreads();
        if (it + 1 < NITER) issueW(it + 1);
        if (tap == 0) {
            // stage A chunk (per-wave): rows 0..63, ci kc*32..+31
            size_t o = ((size_t)b * 64 + lane) * g.Astr + kc * 32;
            const uint4* sh = (const uint4*)(g.Ahi + o);
            const uint4* sl = (const uint4*)(g.Alo + o);
            uint4 a0 = sh[0], a1 = sh[1], a2 = sh[2], a3 = sh[3];
            uint4 c0 = sl[0], c1 = sl[1], c2 = sl[2], c3 = sl[3];
            *(uint4*)&Alds[w][0][lane * 40 + 0]  = a0;
            *(uint4*)&Alds[w][0][lane * 40 + 8]  = a1;
            *(uint4*)&Alds[w][0][lane * 40 + 16] = a2;
            *(uint4*)&Alds[w][0][lane * 40 + 24] = a3;
            *(uint4*)&Alds[w][1][lane * 40 + 0]  = c0;
            *(uint4*)&Alds[w][1][lane * 40 + 8]  = c1;
            *(uint4*)&Alds[w][1][lane * 40 + 16] = c2;
            *(uint4*)&Alds[w][1][lane * 40 + 24] = c3;
        }
        const int dy = tap / 3 - 1, dx = tap % 3 - 1;
        const int q8 = (lane >> 4) * 8;
        const int ml = lane & 15;
        short8 aH[4], aL[4];
#pragma unroll
        for (int mt = 0; mt < 4; ++mt) {
            int px = mt * 16 + ml;
            int yy = (px >> 3) + dy, xx = (px & 7) + dx;
            int row = ((unsigned)yy < 8u && (unsigned)xx < 8u) ? yy * 8 + xx : 64;
            int o = row * 40 + q8;
            aH[mt] = *(const short8*)&Alds[w][0][o];
            aL[mt] = *(const short8*)&Alds[w][1][o];
        }
#pragma unroll
        for (int nn = 0; nn < 4; ++nn) {
            int o = (nn * 16 + ml) * 40 + q8;
            short8 bH = *(const short8*)&Wlds[par][0][o];
            short8 bL = *(const short8*)&Wlds[par][1][o];
#pragma unroll
            for (int mt = 0; mt < 4; ++mt) {
                acc[mt][nn] = __builtin_amdgcn_mfma_f32_16x16x32_bf16(aH[mt], bH, acc[mt][nn], 0, 0, 0);
                acc[mt][nn] = __builtin_amdgcn_mfma_f32_16x16x32_bf16(aH[mt], bL, acc[mt][nn], 0, 0, 0);
                acc[mt][nn] = __builtin_amdgcn_mfma_f32_16x16x32_bf16(aL[mt], bH, acc[mt][nn], 0, 0, 0);
            }
        }
    }
    // epilogue: C layout col=lane&15, row=(lane>>4)*4+reg
    const int q = lane >> 4, ml = lane & 15;
#pragma unroll
    for (int nn = 0; nn < 4; ++nn) {
        int co = n0 + nn * 16 + ml;
        float bv = LD(bias, (size_t)boff + co, isf32);
#pragma unroll
        for (int mt = 0; mt < 4; ++mt) {
            f32x4 v = acc[mt][nn];
            v[0] += bv; v[1] += bv; v[2] += bv; v[3] += bv;
            *(f32x4*)&Out[((size_t)b * CoutT + co) * 64 + mt * 16 + q * 4] = v;
        }
    }
}

// ---------------------------------------------------------------- attention
__global__ __launch_bounds__(256) void attn_kernel(
    const float* __restrict__ kqv,
    const void* __restrict__ k0,
    const void* __restrict__ v0,
    const void* __restrict__ pw,
    const void* __restrict__ pb,
    const float* __restrict__ biasb,
    const int* __restrict__ flags,
    u16* __restrict__ ahi, u16* __restrict__ alo,
    size_t kvoff, size_t pwoff, size_t pboff) {
    __shared__ float q[512], kl[512], vl[512], sc[40], wexp[40];
    const int t = threadIdx.x;
    const int isf32 = flags[0];
    const int b = blockIdx.x >> 3, h = blockIdx.x & 7;
    const size_t kqb = (size_t)b * 192 * 64;
    for (int d = t; d < 512; d += 256) {
        int hd = d >> 6, ss = d & 63;
        q[d]  = kqv[kqb + (h * 24 + 8 + hd) * 64 + ss] * 0.044194173824159216f;
        kl[d] = kqv[kqb + (h * 24 + 0 + hd) * 64 + ss];
        vl[d] = kqv[kqb + (h * 24 + 16 + hd) * 64 + ss];
    }
    __syncthreads();
    const int wid = t >> 6, lane = t & 63;
    const size_t kvbase = kvoff + ((size_t)(b * 8 + h)) * (size_t)(40 * 512);
    for (int m = wid; m < 40; m += 4) {
        float p = 0.f;
        if (isf32) {
#pragma unroll
            for (int i = 0; i < 8; ++i) {
                int d = lane + 64 * i;
                float kc = (m < 39) ? ((const float*)k0)[kvbase + (size_t)(m + 1) * 512 + d] : kl[d];
                kc += ((const float*)pw)[pwoff + (size_t)m * 4096 + h * 512 + d];
                p += q[d] * kc;
            }
        } else {
#pragma unroll
            for (int i = 0; i < 8; ++i) {
                int d = lane + 64 * i;
                float kc = (m < 39) ? __bfloat162float(((const bf16*)k0)[kvbase + (size_t)(m + 1) * 512 + d]) : kl[d];
                kc += __bfloat162float(((const bf16*)pw)[pwoff + (size_t)m * 4096 + h * 512 + d]);
                p += q[d] * kc;
            }
        }
#pragma unroll
        for (int off = 32; off > 0; off >>= 1) p += __shfl_down(p, off, 64);
        if (lane == 0)
            sc[m] = p + biasb[b * 40 + m] + LD(pb, pboff + m * 8 + h, isf32);
    }
    __syncthreads();
    float mx = -1e30f;
    for (int m = 0; m < 40; ++m) mx = fmaxf(mx, sc[m]);
    if (t < 40) wexp[t] = __expf(sc[t] - mx);
    __syncthreads();
    float sum = 0.f;
    for (int m = 0; m < 40; ++m) sum += wexp[m];
    float rs = 1.f / sum;
    for (int d = t; d < 512; d += 256) {
        float acc = 0.f;
        if (isf32) {
            for (int m = 0; m < 39; ++m)
                acc += wexp[m] * ((const float*)v0)[kvbase + (size_t)(m + 1) * 512 + d];
        } else {
            for (int m = 0; m < 39; ++m)
                acc += wexp[m] * __bfloat162float(((const bf16*)v0)[kvbase + (size_t)(m + 1) * 512 + d]);
        }
        acc += wexp[39] * vl[d];
        acc *= rs;
        // write in out-conv A layout: [b][px][ch], hi/lo split
        int ch = h * 8 + (d >> 6), px = d & 63;
        u16 hh, ll; SPLIT(acc, hh, ll);
        size_t o = (size_t)b * 4096 + px * 64 + ch;
        ahi[o] = hh; alo[o] = ll;
    }
}

__global__ __launch_bounds__(256) void ln_final_kernel(
    const float* __restrict__ convo,
    const void* __restrict__ x,
    const float* __restrict__ gates,
    const void* __restrict__ c0,
    const void* __restrict__ notdone,
    const void* __restrict__ lnw,
    const void* __restrict__ lnb,
    const int* __restrict__ flags,
    float* __restrict__ out_buf,
    void* __restrict__ dout, int write_out,
    size_t coff, size_t lnoff) {
    __shared__ float red[8];
    __shared__ float stats[2];
    const int t = threadIdx.x, b = blockIdx.x;
    const int isf32 = flags[0], ndbyte = flags[2];
    const size_t base = (size_t)b * 4096;
    float v[16];
    float sum = 0.f, sumsq = 0.f;
#pragma unroll
    for (int k = 0; k < 16; ++k) {
        int i = t + 256 * k;
        float val = convo[base + i] + LD(x, base + i, isf32);
        v[k] = val; sum += val; sumsq += val * val;
    }
#pragma unroll
    for (int off = 32; off > 0; off >>= 1) {
        sum   += __shfl_down(sum, off, 64);
        sumsq += __shfl_down(sumsq, off, 64);
    }
    const int wid = t >> 6, lane = t & 63;
    if (lane == 0) { red[wid] = sum; red[4 + wid] = sumsq; }
    __syncthreads();
    if (t == 0) {
        float ts = red[0] + red[1] + red[2] + red[3];
        float tq = red[4] + red[5] + red[6] + red[7];
        float mu = ts * (1.f / 4096.f);
        float var = tq * (1.f / 4096.f) - mu * mu;
        stats[0] = mu; stats[1] = rsqrtf(fmaxf(var, 0.f) + 1e-5f);
    }
    __syncthreads();
    float mu = stats[0], rstd = stats[1];
    float nd = (LDB(notdone, b, ndbyte) != 0) ? 1.f : 0.f;
    const size_t gbase = (size_t)b * 320 * 64;
#pragma unroll
    for (int k = 0; k < 16; ++k) {
        int i = t + 256 * k;
        int c = i >> 6, s = i & 63;
        float aon = (v[k] - mu) * rstd * LD(lnw, lnoff + i, isf32) + LD(lnb, lnoff + i, isf32);
        float gi = gates[gbase + (size_t)(c      ) * 64 + s];
        float gf = gates[gbase + (size_t)(c +  64) * 64 + s];
        float go = gates[gbase + (size_t)(c + 128) * 64 + s];
        float gg = gates[gbase + (size_t)(c + 192) * 64 + s];
        float ga = gates[gbase + (size_t)(c + 256) * 64 + s];
        gi = 1.f / (1.f + __expf(-gi));
        gf = 1.f / (1.f + __expf(-gf));
        go = 1.f / (1.f + __expf(-go));
        gg = tanhf(gg);
        ga = 1.f / (1.f + __expf(-ga));
        float cc = LD(c0, coff + base + i, isf32) * nd;
        float cn = gf * cc + gi * gg + ga * tanhf(aon);
        float o  = go * tanhf(cn);
        out_buf[base + i] = o;
        if (write_out) {
            if (isf32) ((float*)dout)[base + i] = o;
            else       ((bf16*)dout)[base + i] = __float2bfloat16(o);
        }
    }
}

extern "C" void kernel_launch(void* const* d_in, const int* in_sizes, int n_in,
                              void* d_out, int out_size, void* d_ws, size_t ws_size,
                              hipStream_t stream) {
    const void* x      = d_in[0];
    const void* h0     = d_in[1];
    const void* c0     = d_in[2];
    const void* k0     = d_in[3];
    const void* v0     = d_in[4];
    const void* src_mask = d_in[5];
    const void* notdone  = d_in[6];
    const void* main_w = d_in[7];
    const void* main_b = d_in[8];
    const void* proj_w = d_in[9];
    const void* proj_b = d_in[10];
    const void* out_w  = d_in[11];
    const void* out_b  = d_in[12];
    const void* ln_w   = d_in[13];
    const void* ln_b   = d_in[14];
    const void* pos_w  = d_in[15];
    const void* pos_b  = d_in[16];

    float* wsf = (float*)d_ws;
    int*   flags    = (int*)d_ws;
    float* bias_buf = wsf + 8;
    float* out_buf  = wsf + 8192;          // 524288 f
    float* gates_buf= wsf + 532480;        // 2621440 f
    float* kqv_buf  = wsf + 3153920;       // 1572864 f
    u16* cin_hi     = (u16*)(wsf + 4726784);   // 1572864 u16
    u16* cin_lo     = (u16*)(wsf + 5513216);   // 1572864 u16
    float* convo_buf= wsf + 4726784;           // alias (cin dead by out-conv)
    u16* attn_hi    = (u16*)(wsf + 5513216);   // alias (cin dead by attn)
    u16* attn_lo    = (u16*)(wsf + 5775360);
    u16* wr_hi      = (u16*)(wsf + 6299648);   // 811008 u16
    u16* wr_lo      = (u16*)(wsf + 6705152);   // end @ 7110656 f = 28.4 MB

    detect_kernel<<<1, 256, 0, stream>>>(x, src_mask, notdone, flags);
    bias_kernel<<<20, 256, 0, stream>>>(src_mask, notdone, flags, bias_buf);
    init_prevout_kernel<<<2048, 256, 0, stream>>>(h0, notdone, flags, out_buf,
                                                  (size_t)524288);
    for (int n = 0; n < 2; ++n) {
        repack_w_kernel<<<3168, 256, 0, stream>>>(main_w, proj_w, out_w, flags,
                                                  wr_hi, wr_lo, n);
        build_cin_t_kernel<<<128, 256, 0, stream>>>(x, out_buf, h0, notdone, flags,
                                                    cin_hi, cin_lo, (size_t)n * 524288);
        ConvArgs ga;
        ga.Ahi = cin_hi; ga.Alo = cin_lo; ga.Astr = 192;
        ga.WhiA = wr_hi;          ga.WloA = wr_lo;          ga.KciA = 192; ga.CoutA = 320;
        ga.WhiB = wr_hi + 552960; ga.WloB = wr_lo + 552960; ga.KciB = 128; ga.CoutB = 192;
        ga.biasA = main_b; ga.boffA = (long long)n * 320; ga.OutA = gates_buf;
        ga.biasB = proj_b; ga.boffB = (long long)n * 192; ga.OutB = kqv_buf;
        ga.ntA = 5; ga.NT = 8;
        conv_mfma_kernel<<<256, 256, 0, stream>>>(ga, flags);

        attn_kernel<<<1024, 256, 0, stream>>>(
            kqv_buf, k0, v0, pos_w, pos_b, bias_buf, flags, attn_hi, attn_lo,
            (size_t)n * 20971520, (size_t)n * 163840, (size_t)n * 320);

        ConvArgs oa;
        oa.Ahi = attn_hi; oa.Alo = attn_lo; oa.Astr = 64;
        oa.WhiA = wr_hi + 774144; oa.WloA = wr_lo + 774144; oa.KciA = 64; oa.CoutA = 64;
        oa.WhiB = oa.WhiA; oa.WloB = oa.WloA; oa.KciB = 64; oa.CoutB = 64;
        oa.biasA = out_b; oa.boffA = (long long)n * 64; oa.OutA = convo_buf;
        oa.biasB = out_b; oa.boffB = (long long)n * 64; oa.OutB = convo_buf;
        oa.ntA = 1; oa.NT = 1;
        conv_mfma_kernel<<<32, 256, 0, stream>>>(oa, flags);

        ln_final_kernel<<<128, 256, 0, stream>>>(
            convo_buf, x, gates_buf, c0, notdone, ln_w, ln_b, flags,
            out_buf, d_out, (n == 1) ? 1 : 0,
            (size_t)n * 524288, (size_t)n * 4096);
    }
}